// Round 10
// baseline (289.329 us; speedup 1.0000x reference)
//
#include <hip/hip_runtime.h>
#include <math.h>

#define KW 65
#define L_LEN 65536
#define B_N 32
#define OC_N 64
#define KPAD 160      // two 80-wide channel sections
#define SEC 80
#define LT 256        // l per tile
#define NT 8          // tiles per block
#define LGRP (LT*NT)  // 2048 l per block
#define XBASE 344     // phase-copy length in shorts (86 granules of 4)

typedef __attribute__((ext_vector_type(8))) short short8;
typedef __attribute__((ext_vector_type(4))) float f32x4;

__device__ __forceinline__ unsigned short f2bf(float f) {
    unsigned u = __builtin_bit_cast(unsigned, f);
    unsigned r = u + 0x7FFFu + ((u >> 16) & 1u);
    return (unsigned short)(r >> 16);
}

__device__ __forceinline__ unsigned pk2(float a, float b) {
    return (unsigned)f2bf(a) | ((unsigned)f2bf(b) << 16);
}

__device__ __forceinline__ float nan0(float v) {
    if (isnan(v)) return 0.0f;
    if (isinf(v)) return v > 0.0f ? 3.4028234663852886e38f : -3.4028234663852886e38f;
    return v;
}

// ---------------- Kernel A: steered weights, packed bf16 [B][OC][160] -------
// grid (8, B): block handles batch b x 8 ocs -> short latency chains.
__global__ __launch_bounds__(256) void steer_weights(
        const int* __restrict__ z, const float* __restrict__ s,
        const float* __restrict__ bw, unsigned short* __restrict__ wpk) {
    const float PI = 3.14159265358979323846f;
    const float FS = 50000000.0f;
    int ocg = blockIdx.x;
    int b   = blockIdx.y;
    int t   = threadIdx.x;

    const int*   zb = z + b * 5;
    const float* sb = s + b * 5;
    float f0    = (zb[0] > 0) ? nan0(sb[0]) : 0.0f;
    float alpha = (zb[1] > 0) ? nan0(sb[1]) : 1.0f;
    float gain  = (zb[2] > 0) ? nan0(sb[2]) : 1.0f;
    float shf   = (zb[3] > 0) ? nan0(sb[3]) : 0.0f;
    float chirp = (zb[4] > 0) ? nan0(sb[4]) : 0.0f;

    float a = fmaxf(alpha, 0.001f);
    float Nf_raw = rintf(65.0f / a);          // jnp.round = half-to-even
    int   N  = (int)fminf(fmaxf(Nf_raw, 1.0f), 130.0f);
    float Nf = (float)N;
    int   sh = (int)rintf(shf);

    __shared__ float rw[8][2][KW];
    __shared__ float cph[KW], sph[KW];
    __shared__ int   j0t[KW], j1t[KW];
    __shared__ float w2t[KW];
    __shared__ int   i0t[130], i1t[130];
    __shared__ float w1t[130];

    if (t < KW) {
        float n  = (float)t;
        float tt = n / FS;
        float phi = 2.0f * PI * f0 * n / FS + PI * chirp * tt * tt;
        cph[t] = cosf(phi);
        sph[t] = sinf(phi);
        float c2  = fmaxf(((float)t + 0.5f) * (Nf / 65.0f) - 0.5f, 0.0f);
        float j0f = floorf(c2);
        j0t[t] = (int)j0f;
        j1t[t] = min((int)j0f + 1, N - 1);
        w2t[t] = c2 - j0f;
    } else if (t < KW + 130) {
        int j = t - KW;
        float c   = fmaxf(((float)j + 0.5f) * (65.0f / Nf) - 0.5f, 0.0f);
        float i0f = floorf(c);
        int   i0  = min((int)i0f, KW - 1);
        i0t[j] = i0;
        i1t[j] = min(i0 + 1, KW - 1);
        w1t[j] = c - i0f;
    }
    __syncthreads();

    // resample: 16 rows x 65 taps via table lerps
    for (int item = t; item < 16 * KW; item += 256) {
        int row = item / KW, i = item % KW;     // row = ocl*2 + ch
        const float* w = bw + (((ocg * 8 + (row >> 1)) * 2) + (row & 1)) * KW;
        int j0 = j0t[i], j1 = j1t[i];
        float v0 = (1.0f - w1t[j0]) * w[i0t[j0]] + w1t[j0] * w[i1t[j0]];
        float v1 = (1.0f - w1t[j1]) * w[i0t[j1]] + w1t[j1] * w[i1t[j1]];
        rw[row >> 1][row & 1][i] = (1.0f - w2t[i]) * v0 + w2t[i] * v1;
    }
    __syncthreads();

    int sh0 = ((sh % KW) + KW) % KW;
    // mix + gain + shift + pack
    for (int item = t; item < 8 * KW; item += 256) {
        int ocl = item / KW, k = item % KW;
        unsigned short* ob = wpk + ((size_t)b * OC_N + ocg * 8 + ocl) * KPAD;
        float I = rw[ocl][0][k], Q = rw[ocl][1][k];
        float cp = cph[k], sp = sph[k];
        float Ip = (I * cp - Q * sp) * gain;
        float Qp = (I * sp + Q * cp) * gain;
        int kk = k + sh0; if (kk >= KW) kk -= KW;
        ob[kk]       = f2bf(Ip);
        ob[SEC + kk] = f2bf(Qp);
    }
    // zero padding taps 65..79 of both sections
    for (int item = t; item < 8 * 30; item += 256) {
        int ocl = item / 30, rem = item % 30;
        int sec = rem / 15, kk = KW + rem % 15;
        unsigned short* ob = wpk + ((size_t)b * OC_N + ocg * 8 + ocl) * KPAD;
        ob[sec * SEC + kk] = 0;
    }
}

// ---------------- Kernel B: implicit-GEMM conv via bf16 MFMA -----------------
// R4 tile math (64 oc x 2048 l, 8 tiles of 256, 4 waves, double-buffered
// 8-phase LDS copies) with SINGLE-PASS staging and ONE __syncthreads/tile:
// 172 loader threads each own a 4-short granule for ALL 8 phases (12-float
// window in regs -> 8 uint2 writes, odd phases via in-register funnels).
// Schedule: stage(t) -> barrier -> issue load(t+1) -> MFMA(t) -> stores(t):
// prefetch hides under a full MFMA phase; stores half-drained at next barrier.
__global__ __launch_bounds__(256, 3) void steer_conv_mfma(
        const float* __restrict__ x, const unsigned short* __restrict__ wpk,
        float* __restrict__ y) {
    int b   = blockIdx.y;
    int L0  = blockIdx.x * LGRP;
    int tid = threadIdx.x;
    int wv = tid >> 6, lane = tid & 63;
    int c = lane & 15, g = lane >> 4;
    int a = wv & 1, lsub = wv >> 1;

    __shared__ __align__(16) unsigned short xt[2][8][2][XBASE];  // 22 KB

    // A fragments (weights) loaded once per block
    short8 afr[2][5];
    #pragma unroll
    for (int ot = 0; ot < 2; ++ot) {
        const unsigned short* wb = wpk + ((size_t)b * OC_N + 32 * a + 16 * ot + c) * KPAD;
        #pragma unroll
        for (int s = 0; s < 5; ++s)
            afr[ot][s] = *(const short8*)(wb + 32 * s + 8 * g);
    }

    const float* xb = x + (size_t)b * 2 * L_LEN;

    bool isLdr = (tid < 172);
    int lch = tid / 86, lg4 = tid % 86;   // granule: shorts [4*lg4, 4*lg4+4)

    // per-lane B-fragment element offsets (shorts) within a phase copy
    int boff[5];
    #pragma unroll
    for (int s = 0; s < 5; ++s) {
        int k0 = 32 * s + 8 * g;
        int ch = (k0 >= SEC) ? 1 : 0;
        int t0 = k0 - SEC * ch;
        boff[s] = ch * XBASE + 128 * lsub + 8 * c + t0;   // *2B -> 16B aligned
    }

    auto ldf4 = [&](int gi) -> float4 {
        if (gi >= 0 && gi + 3 < L_LEN)
            return *(const float4*)(xb + (size_t)lch * L_LEN + gi);
        float tmp[4];
        #pragma unroll
        for (int u = 0; u < 4; ++u) {
            int q = gi + u;
            tmp[u] = (q >= 0 && q < L_LEN) ? xb[(size_t)lch * L_LEN + q] : 0.0f;
        }
        return make_float4(tmp[0], tmp[1], tmp[2], tmp[3]);
    };

    // loader window: base shorts [4*lg4, 4*lg4+12) of tile t
    float4 w4[3];
    #pragma unroll
    for (int k = 0; k < 3; ++k) w4[k] = make_float4(0.f, 0.f, 0.f, 0.f);
    if (isLdr) {
        int gi0 = L0 - 32 + 4 * lg4;
        #pragma unroll
        for (int k = 0; k < 3; ++k) w4[k] = ldf4(gi0 + 4 * k);
    }

    int cur = 0;
    for (int t = 0; t < NT; ++t) {
        int l0 = L0 + t * LT;
        // single-pass stage: all 8 phase copies, granule per loader thread
        if (isLdr) {
            unsigned u6[6];
            u6[0] = pk2(w4[0].x, w4[0].y); u6[1] = pk2(w4[0].z, w4[0].w);
            u6[2] = pk2(w4[1].x, w4[1].y); u6[3] = pk2(w4[1].z, w4[1].w);
            u6[4] = pk2(w4[2].x, w4[2].y); u6[5] = pk2(w4[2].z, w4[2].w);
            #pragma unroll
            for (int p = 0; p < 8; ++p) {
                int q = p >> 1;
                uint2 o;
                if (p & 1)
                    o = make_uint2((u6[q]     >> 16) | (u6[q + 1] << 16),
                                   (u6[q + 1] >> 16) | (u6[q + 2] << 16));
                else
                    o = make_uint2(u6[q], u6[q + 1]);
                *(uint2*)&xt[cur][p][lch][4 * lg4] = o;
            }
        }
        __syncthreads();

        // issue next tile's window loads; consumed next iter (fully hidden)
        if (isLdr && t + 1 < NT) {
            int gi0 = l0 + LT - 32 + 4 * lg4;
            #pragma unroll
            for (int k = 0; k < 3; ++k) w4[k] = ldf4(gi0 + 4 * k);
        }

        f32x4 acc[2][8];
        #pragma unroll
        for (int ot = 0; ot < 2; ++ot)
            #pragma unroll
            for (int p = 0; p < 8; ++p) acc[ot][p] = (f32x4){0.f, 0.f, 0.f, 0.f};

        #pragma unroll
        for (int p = 0; p < 8; ++p) {
            const unsigned short* xp = &xt[cur][p][0][0];
            #pragma unroll
            for (int s = 0; s < 5; ++s) {
                short8 bfr = *(const short8*)(xp + boff[s]);
                acc[0][p] = __builtin_amdgcn_mfma_f32_16x16x32_bf16(afr[0][s], bfr, acc[0][p], 0, 0, 0);
                acc[1][p] = __builtin_amdgcn_mfma_f32_16x16x32_bf16(afr[1][s], bfr, acc[1][p], 0, 0, 0);
            }
            if (p == 3) {       // lo-half stores: extra ACK head start
                #pragma unroll
                for (int ot = 0; ot < 2; ++ot)
                    #pragma unroll
                    for (int r = 0; r < 4; ++r) {
                        int oc = 32 * a + 16 * ot + 4 * g + r;
                        float* yr = y + ((size_t)b * OC_N + oc) * L_LEN + l0 + 128 * lsub + 8 * c;
                        *(f32x4*)yr = (f32x4){ acc[ot][0][r], acc[ot][1][r], acc[ot][2][r], acc[ot][3][r] };
                    }
            }
            if (p == 7) {       // hi-half stores
                #pragma unroll
                for (int ot = 0; ot < 2; ++ot)
                    #pragma unroll
                    for (int r = 0; r < 4; ++r) {
                        int oc = 32 * a + 16 * ot + 4 * g + r;
                        float* yr = y + ((size_t)b * OC_N + oc) * L_LEN + l0 + 128 * lsub + 8 * c + 4;
                        *(f32x4*)yr = (f32x4){ acc[ot][4][r], acc[ot][5][r], acc[ot][6][r], acc[ot][7][r] };
                    }
            }
        }
        cur ^= 1;
    }
}

extern "C" void kernel_launch(void* const* d_in, const int* in_sizes, int n_in,
                              void* d_out, int out_size, void* d_ws, size_t ws_size,
                              hipStream_t stream) {
    const float* x  = (const float*)d_in[0];
    const int*   z  = (const int*)d_in[1];
    const float* s  = (const float*)d_in[2];
    const float* bw = (const float*)d_in[3];
    float* y = (float*)d_out;
    unsigned short* wpk = (unsigned short*)d_ws;   // 32*64*160*2 = 655 KB

    steer_weights<<<dim3(8, B_N), dim3(256), 0, stream>>>(z, s, bw, wpk);
    steer_conv_mfma<<<dim3(L_LEN / LGRP, B_N), dim3(256), 0, stream>>>(x, wpk, y);
}

// Round 11
// 188.508 us; speedup vs baseline: 1.5348x; 1.5348x over previous
//
#include <hip/hip_runtime.h>
#include <math.h>

#define KW 65
#define L_LEN 65536
#define B_N 32
#define OC_N 64
#define KPAD 160      // two 80-wide channel sections
#define SEC 80
#define LT 256        // l per tile
#define NT 8          // tiles per block
#define LGRP (LT*NT)  // 2048 l per block
#define XBASE 344     // base (phase-0) window length in shorts, mult of 8

typedef __attribute__((ext_vector_type(8))) short short8;
typedef __attribute__((ext_vector_type(4))) float f32x4;

__device__ __forceinline__ unsigned short f2bf(float f) {
    unsigned u = __builtin_bit_cast(unsigned, f);
    unsigned r = u + 0x7FFFu + ((u >> 16) & 1u);
    return (unsigned short)(r >> 16);
}

__device__ __forceinline__ float nan0(float v) {
    if (isnan(v)) return 0.0f;
    if (isinf(v)) return v > 0.0f ? 3.4028234663852886e38f : -3.4028234663852886e38f;
    return v;
}

// ---------------- Kernel A: steered weights, packed bf16 [B][OC][160] -------
// grid (8, B): block handles batch b x 8 ocs -> short latency chains.
__global__ __launch_bounds__(256) void steer_weights(
        const int* __restrict__ z, const float* __restrict__ s,
        const float* __restrict__ bw, unsigned short* __restrict__ wpk) {
    const float PI = 3.14159265358979323846f;
    const float FS = 50000000.0f;
    int ocg = blockIdx.x;
    int b   = blockIdx.y;
    int t   = threadIdx.x;

    const int*   zb = z + b * 5;
    const float* sb = s + b * 5;
    float f0    = (zb[0] > 0) ? nan0(sb[0]) : 0.0f;
    float alpha = (zb[1] > 0) ? nan0(sb[1]) : 1.0f;
    float gain  = (zb[2] > 0) ? nan0(sb[2]) : 1.0f;
    float shf   = (zb[3] > 0) ? nan0(sb[3]) : 0.0f;
    float chirp = (zb[4] > 0) ? nan0(sb[4]) : 0.0f;

    float a = fmaxf(alpha, 0.001f);
    float Nf_raw = rintf(65.0f / a);          // jnp.round = half-to-even
    int   N  = (int)fminf(fmaxf(Nf_raw, 1.0f), 130.0f);
    float Nf = (float)N;
    int   sh = (int)rintf(shf);

    __shared__ float rw[8][2][KW];
    __shared__ float cph[KW], sph[KW];
    __shared__ int   j0t[KW], j1t[KW];
    __shared__ float w2t[KW];
    __shared__ int   i0t[130], i1t[130];
    __shared__ float w1t[130];

    if (t < KW) {
        float n  = (float)t;
        float tt = n / FS;
        float phi = 2.0f * PI * f0 * n / FS + PI * chirp * tt * tt;
        cph[t] = cosf(phi);
        sph[t] = sinf(phi);
        float c2  = fmaxf(((float)t + 0.5f) * (Nf / 65.0f) - 0.5f, 0.0f);
        float j0f = floorf(c2);
        j0t[t] = (int)j0f;
        j1t[t] = min((int)j0f + 1, N - 1);
        w2t[t] = c2 - j0f;
    } else if (t < KW + 130) {
        int j = t - KW;
        float c   = fmaxf(((float)j + 0.5f) * (65.0f / Nf) - 0.5f, 0.0f);
        float i0f = floorf(c);
        int   i0  = min((int)i0f, KW - 1);
        i0t[j] = i0;
        i1t[j] = min(i0 + 1, KW - 1);
        w1t[j] = c - i0f;
    }
    __syncthreads();

    // resample: 16 rows x 65 taps via table lerps
    for (int item = t; item < 16 * KW; item += 256) {
        int row = item / KW, i = item % KW;     // row = ocl*2 + ch
        const float* w = bw + (((ocg * 8 + (row >> 1)) * 2) + (row & 1)) * KW;
        int j0 = j0t[i], j1 = j1t[i];
        float v0 = (1.0f - w1t[j0]) * w[i0t[j0]] + w1t[j0] * w[i1t[j0]];
        float v1 = (1.0f - w1t[j1]) * w[i0t[j1]] + w1t[j1] * w[i1t[j1]];
        rw[row >> 1][row & 1][i] = (1.0f - w2t[i]) * v0 + w2t[i] * v1;
    }
    __syncthreads();

    int sh0 = ((sh % KW) + KW) % KW;
    // mix + gain + shift + pack
    for (int item = t; item < 8 * KW; item += 256) {
        int ocl = item / KW, k = item % KW;
        unsigned short* ob = wpk + ((size_t)b * OC_N + ocg * 8 + ocl) * KPAD;
        float I = rw[ocl][0][k], Q = rw[ocl][1][k];
        float cp = cph[k], sp = sph[k];
        float Ip = (I * cp - Q * sp) * gain;
        float Qp = (I * sp + Q * cp) * gain;
        int kk = k + sh0; if (kk >= KW) kk -= KW;
        ob[kk]       = f2bf(Ip);
        ob[SEC + kk] = f2bf(Qp);
    }
    // zero padding taps 65..79 of both sections
    for (int item = t; item < 8 * 30; item += 256) {
        int ocl = item / 30, rem = item % 30;
        int sec = rem / 15, kk = KW + rem % 15;
        unsigned short* ob = wpk + ((size_t)b * OC_N + ocg * 8 + ocl) * KPAD;
        ob[sec * SEC + kk] = 0;
    }
}

// ---------------- Kernel B: implicit-GEMM conv via bf16 MFMA -----------------
// R4 structure verbatim (64 oc x 2048 l per block, 8 tiles of 256, 4 waves,
// double-buffered 8-phase LDS copies, 2 __syncthreads per tile). ONE change:
// __launch_bounds__(256,4) -> 4 blocks/CU (exact-fit grid 1024 = 4*256, zero
// tail, 16 waves/CU) so blocks desynchronize and one block's LDS/MFMA overlaps
// another block's store-queue stalls.
__global__ __launch_bounds__(256, 4) void steer_conv_mfma(
        const float* __restrict__ x, const unsigned short* __restrict__ wpk,
        float* __restrict__ y) {
    int b   = blockIdx.y;
    int L0  = blockIdx.x * LGRP;
    int tid = threadIdx.x;
    int wv = tid >> 6, lane = tid & 63;
    int c = lane & 15, g = lane >> 4;
    int a = wv & 1, lsub = wv >> 1;

    __shared__ __align__(16) unsigned short xt[2][8][2][XBASE];  // 22 KB

    // A fragments (weights) loaded once per block
    short8 afr[2][5];
    #pragma unroll
    for (int ot = 0; ot < 2; ++ot) {
        const unsigned short* wb = wpk + ((size_t)b * OC_N + 32 * a + 16 * ot + c) * KPAD;
        #pragma unroll
        for (int s = 0; s < 5; ++s)
            afr[ot][s] = *(const short8*)(wb + 32 * s + 8 * g);
    }

    bool isLoader = (tid >= 84);
    int lidx = tid - 84;
    int lch = lidx / 86, li4 = lidx % 86;
    const float* xrow = x + ((size_t)b * 2 + (isLoader ? lch : 0)) * L_LEN;
    // interior blocks (all but first/last l-group) never touch array edges
    bool interior = (L0 >= 32) && (L0 + LGRP - 32 + 4 * 85 + 3 < L_LEN);

    // per-lane B-fragment element offsets (shorts) within a phase copy
    int boff[5];
    #pragma unroll
    for (int s = 0; s < 5; ++s) {
        int k0 = 32 * s + 8 * g;
        int ch = (k0 >= SEC) ? 1 : 0;
        int t0 = k0 - SEC * ch;
        boff[s] = ch * XBASE + 128 * lsub + 8 * c + t0;   // *2B -> 16B aligned
    }

    auto loadwin = [&](int l0) -> float4 {
        int gi = l0 - 32 + 4 * li4;
        if (interior || (gi >= 0 && gi + 3 < L_LEN))
            return *(const float4*)(xrow + gi);
        float tmp[4];
        #pragma unroll
        for (int u = 0; u < 4; ++u) {
            int q = gi + u;
            tmp[u] = (q >= 0 && q < L_LEN) ? xrow[q] : 0.0f;
        }
        return make_float4(tmp[0], tmp[1], tmp[2], tmp[3]);
    };

    float4 v = make_float4(0.f, 0.f, 0.f, 0.f);
    if (isLoader) v = loadwin(L0);

    int cur = 0;
    for (int t = 0; t < NT; ++t) {
        int l0 = L0 + t * LT;
        // write bf16 base copy (phase 0) of tile t
        if (isLoader) {
            unsigned r0 = (unsigned)f2bf(v.x) | ((unsigned)f2bf(v.y) << 16);
            unsigned r1 = (unsigned)f2bf(v.z) | ((unsigned)f2bf(v.w) << 16);
            *(uint2*)&xt[cur][0][lch][4 * li4] = make_uint2(r0, r1);
        }
        __syncthreads();
        if (tid < 84) {
            // build phases 1..7 by 16-bit funnel shifts of the base copy
            int ch = tid / 42, j = tid % 42;
            const unsigned* src = (const unsigned*)&xt[cur][0][ch][8 * j];
            unsigned d[8];
            #pragma unroll
            for (int i = 0; i < 8; ++i) d[i] = src[i];
            #pragma unroll
            for (int p = 1; p < 8; ++p) {
                int q = p >> 1;
                unsigned o[4];
                #pragma unroll
                for (int i = 0; i < 4; ++i)
                    o[i] = (p & 1) ? ((d[i + q] >> 16) | (d[i + q + 1] << 16)) : d[i + q];
                *(uint4*)&xt[cur][p][ch][8 * j] = make_uint4(o[0], o[1], o[2], o[3]);
            }
        } else if (t + 1 < NT) {
            // prefetch next tile's window into registers
            v = loadwin(l0 + LT);
        }
        __syncthreads();

        f32x4 acc[2][8];
        #pragma unroll
        for (int ot = 0; ot < 2; ++ot)
            #pragma unroll
            for (int p = 0; p < 8; ++p) acc[ot][p] = (f32x4){0.f, 0.f, 0.f, 0.f};

        #pragma unroll
        for (int p = 0; p < 8; ++p) {
            const unsigned short* xp = &xt[cur][p][0][0];
            #pragma unroll
            for (int s = 0; s < 5; ++s) {
                short8 bfr = *(const short8*)(xp + boff[s]);
                acc[0][p] = __builtin_amdgcn_mfma_f32_16x16x32_bf16(afr[0][s], bfr, acc[0][p], 0, 0, 0);
                acc[1][p] = __builtin_amdgcn_mfma_f32_16x16x32_bf16(afr[1][s], bfr, acc[1][p], 0, 0, 0);
            }
        }

        // store: lane holds 8 contiguous l per (ot, r): l = l0+128*lsub+8c+p
        #pragma unroll
        for (int ot = 0; ot < 2; ++ot) {
            #pragma unroll
            for (int r = 0; r < 4; ++r) {
                int oc = 32 * a + 16 * ot + 4 * g + r;
                float* yr = y + ((size_t)b * OC_N + oc) * L_LEN + l0 + 128 * lsub + 8 * c;
                f32x4 lo = { acc[ot][0][r], acc[ot][1][r], acc[ot][2][r], acc[ot][3][r] };
                f32x4 hi = { acc[ot][4][r], acc[ot][5][r], acc[ot][6][r], acc[ot][7][r] };
                *(f32x4*)yr       = lo;
                *((f32x4*)yr + 1) = hi;
            }
        }
        cur ^= 1;
    }
}

extern "C" void kernel_launch(void* const* d_in, const int* in_sizes, int n_in,
                              void* d_out, int out_size, void* d_ws, size_t ws_size,
                              hipStream_t stream) {
    const float* x  = (const float*)d_in[0];
    const int*   z  = (const int*)d_in[1];
    const float* s  = (const float*)d_in[2];
    const float* bw = (const float*)d_in[3];
    float* y = (float*)d_out;
    unsigned short* wpk = (unsigned short*)d_ws;   // 32*64*160*2 = 655 KB

    steer_weights<<<dim3(8, B_N), dim3(256), 0, stream>>>(z, s, bw, wpk);
    steer_conv_mfma<<<dim3(L_LEN / LGRP, B_N), dim3(256), 0, stream>>>(x, wpk, y);
}

// Round 12
// 135.473 us; speedup vs baseline: 2.1357x; 1.3915x over previous
//
#include <hip/hip_runtime.h>
#include <math.h>

#define KW 65
#define L_LEN 65536
#define B_N 32
#define OC_N 64
#define KPAD 160      // two 80-wide channel sections
#define SEC 80
#define LT 256        // l per tile
#define NT 8          // tiles per block
#define LGRP (LT*NT)  // 2048 l per block
#define XBASE 344     // base (phase-0) window length in shorts, mult of 8

typedef __attribute__((ext_vector_type(8))) short short8;
typedef __attribute__((ext_vector_type(4))) short short4v;
typedef __attribute__((ext_vector_type(4))) float f32x4;

__device__ __forceinline__ unsigned short f2bf(float f) {
    unsigned u = __builtin_bit_cast(unsigned, f);
    unsigned r = u + 0x7FFFu + ((u >> 16) & 1u);
    return (unsigned short)(r >> 16);
}

__device__ __forceinline__ float nan0(float v) {
    if (isnan(v)) return 0.0f;
    if (isinf(v)) return v > 0.0f ? 3.4028234663852886e38f : -3.4028234663852886e38f;
    return v;
}

// ---------------- Kernel A: steered weights, packed bf16 [B][OC][160] -------
// grid (8, B): block handles batch b x 8 ocs -> short latency chains.
__global__ __launch_bounds__(256) void steer_weights(
        const int* __restrict__ z, const float* __restrict__ s,
        const float* __restrict__ bw, unsigned short* __restrict__ wpk) {
    const float PI = 3.14159265358979323846f;
    const float FS = 50000000.0f;
    int ocg = blockIdx.x;
    int b   = blockIdx.y;
    int t   = threadIdx.x;

    const int*   zb = z + b * 5;
    const float* sb = s + b * 5;
    float f0    = (zb[0] > 0) ? nan0(sb[0]) : 0.0f;
    float alpha = (zb[1] > 0) ? nan0(sb[1]) : 1.0f;
    float gain  = (zb[2] > 0) ? nan0(sb[2]) : 1.0f;
    float shf   = (zb[3] > 0) ? nan0(sb[3]) : 0.0f;
    float chirp = (zb[4] > 0) ? nan0(sb[4]) : 0.0f;

    float a = fmaxf(alpha, 0.001f);
    float Nf_raw = rintf(65.0f / a);          // jnp.round = half-to-even
    int   N  = (int)fminf(fmaxf(Nf_raw, 1.0f), 130.0f);
    float Nf = (float)N;
    int   sh = (int)rintf(shf);

    __shared__ float rw[8][2][KW];
    __shared__ float cph[KW], sph[KW];
    __shared__ int   j0t[KW], j1t[KW];
    __shared__ float w2t[KW];
    __shared__ int   i0t[130], i1t[130];
    __shared__ float w1t[130];

    if (t < KW) {
        float n  = (float)t;
        float tt = n / FS;
        float phi = 2.0f * PI * f0 * n / FS + PI * chirp * tt * tt;
        cph[t] = cosf(phi);
        sph[t] = sinf(phi);
        float c2  = fmaxf(((float)t + 0.5f) * (Nf / 65.0f) - 0.5f, 0.0f);
        float j0f = floorf(c2);
        j0t[t] = (int)j0f;
        j1t[t] = min((int)j0f + 1, N - 1);
        w2t[t] = c2 - j0f;
    } else if (t < KW + 130) {
        int j = t - KW;
        float c   = fmaxf(((float)j + 0.5f) * (65.0f / Nf) - 0.5f, 0.0f);
        float i0f = floorf(c);
        int   i0  = min((int)i0f, KW - 1);
        i0t[j] = i0;
        i1t[j] = min(i0 + 1, KW - 1);
        w1t[j] = c - i0f;
    }
    __syncthreads();

    // resample: 16 rows x 65 taps via table lerps
    for (int item = t; item < 16 * KW; item += 256) {
        int row = item / KW, i = item % KW;     // row = ocl*2 + ch
        const float* w = bw + (((ocg * 8 + (row >> 1)) * 2) + (row & 1)) * KW;
        int j0 = j0t[i], j1 = j1t[i];
        float v0 = (1.0f - w1t[j0]) * w[i0t[j0]] + w1t[j0] * w[i1t[j0]];
        float v1 = (1.0f - w1t[j1]) * w[i0t[j1]] + w1t[j1] * w[i1t[j1]];
        rw[row >> 1][row & 1][i] = (1.0f - w2t[i]) * v0 + w2t[i] * v1;
    }
    __syncthreads();

    int sh0 = ((sh % KW) + KW) % KW;
    // mix + gain + shift + pack
    for (int item = t; item < 8 * KW; item += 256) {
        int ocl = item / KW, k = item % KW;
        unsigned short* ob = wpk + ((size_t)b * OC_N + ocg * 8 + ocl) * KPAD;
        float I = rw[ocl][0][k], Q = rw[ocl][1][k];
        float cp = cph[k], sp = sph[k];
        float Ip = (I * cp - Q * sp) * gain;
        float Qp = (I * sp + Q * cp) * gain;
        int kk = k + sh0; if (kk >= KW) kk -= KW;
        ob[kk]       = f2bf(Ip);
        ob[SEC + kk] = f2bf(Qp);
    }
    // zero padding taps 65..79 of both sections
    for (int item = t; item < 8 * 30; item += 256) {
        int ocl = item / 30, rem = item % 30;
        int sec = rem / 15, kk = KW + rem % 15;
        unsigned short* ob = wpk + ((size_t)b * OC_N + ocg * 8 + ocl) * KPAD;
        ob[sec * SEC + kk] = 0;
    }
}

// ---------------- Kernel B: implicit-GEMM conv via bf16 MFMA -----------------
// R4 schedule verbatim (64 oc x 2048 l per block, 8 tiles of 256, 4 waves,
// double-buffered LDS, loader/builder split, 2 __syncthreads per tile,
// __launch_bounds__(256,3)). ONE structural change: 4 phase copies with
// l = 64q + 4c + p (q = column-set 0/1) instead of 8 phases with l = 8c + p.
// Each (ot,q,r) store is now one f32x4 with 16B lane stride -> fully
// contiguous 256B per 16-lane group, no partial-line writes.
__global__ __launch_bounds__(256, 3) void steer_conv_mfma(
        const float* __restrict__ x, const unsigned short* __restrict__ wpk,
        float* __restrict__ y) {
    int b   = blockIdx.y;
    int L0  = blockIdx.x * LGRP;
    int tid = threadIdx.x;
    int wv = tid >> 6, lane = tid & 63;
    int c = lane & 15, g = lane >> 4;
    int a = wv & 1, lsub = wv >> 1;

    __shared__ __align__(16) unsigned short xt[2][4][2][XBASE];  // 11 KB

    // A fragments (weights) loaded once per block
    short8 afr[2][5];
    #pragma unroll
    for (int ot = 0; ot < 2; ++ot) {
        const unsigned short* wb = wpk + ((size_t)b * OC_N + 32 * a + 16 * ot + c) * KPAD;
        #pragma unroll
        for (int s = 0; s < 5; ++s)
            afr[ot][s] = *(const short8*)(wb + 32 * s + 8 * g);
    }

    const float* xb = x + (size_t)b * 2 * L_LEN;

    bool isLoader = (tid >= 84);
    int lidx = tid - 84;
    int lch = lidx / 86, li4 = lidx % 86;

    // per-lane B-fragment base (shorts) within a phase copy, per k-step;
    // actual read at boff[s] + 64*q + 4*c (8B aligned)
    int boff[5];
    #pragma unroll
    for (int s = 0; s < 5; ++s) {
        int k0 = 32 * s + 8 * g;
        int ch = (k0 >= SEC) ? 1 : 0;
        int t0 = k0 - SEC * ch;
        boff[s] = ch * XBASE + 128 * lsub + t0;
    }

    auto loadwin = [&](int l0) -> float4 {
        int gi = l0 - 32 + 4 * li4;
        float4 v;
        if (gi >= 0 && gi + 3 < L_LEN) {
            v = *(const float4*)(xb + (size_t)lch * L_LEN + gi);
        } else {
            float tmp[4];
            #pragma unroll
            for (int u = 0; u < 4; ++u) {
                int q = gi + u;
                tmp[u] = (q >= 0 && q < L_LEN) ? xb[(size_t)lch * L_LEN + q] : 0.0f;
            }
            v = make_float4(tmp[0], tmp[1], tmp[2], tmp[3]);
        }
        return v;
    };

    float4 v = make_float4(0.f, 0.f, 0.f, 0.f);
    if (isLoader) v = loadwin(L0);

    int cur = 0;
    for (int t = 0; t < NT; ++t) {
        int l0 = L0 + t * LT;
        // write bf16 base copy (phase 0) of tile t
        if (isLoader) {
            unsigned r0 = (unsigned)f2bf(v.x) | ((unsigned)f2bf(v.y) << 16);
            unsigned r1 = (unsigned)f2bf(v.z) | ((unsigned)f2bf(v.w) << 16);
            *(uint2*)&xt[cur][0][lch][4 * li4] = make_uint2(r0, r1);
        }
        __syncthreads();
        if (tid < 84) {
            // build phases 1..3 by 16-bit funnel shifts of the base copy
            int ch = tid / 42, j = tid % 42;
            const unsigned* src = (const unsigned*)&xt[cur][0][ch][8 * j];
            unsigned d[8];
            #pragma unroll
            for (int i = 0; i < 8; ++i) d[i] = src[i];
            #pragma unroll
            for (int p = 1; p < 4; ++p) {
                int q = p >> 1;
                unsigned o[4];
                #pragma unroll
                for (int i = 0; i < 4; ++i)
                    o[i] = (p & 1) ? ((d[i + q] >> 16) | (d[i + q + 1] << 16)) : d[i + q];
                *(uint4*)&xt[cur][p][ch][8 * j] = make_uint4(o[0], o[1], o[2], o[3]);
            }
        } else if (t + 1 < NT) {
            // prefetch next tile's window into registers
            v = loadwin(l0 + LT);
        }
        __syncthreads();

        f32x4 acc[2][2][4];   // [ot][q][p]
        #pragma unroll
        for (int ot = 0; ot < 2; ++ot)
            #pragma unroll
            for (int q = 0; q < 2; ++q)
                #pragma unroll
                for (int p = 0; p < 4; ++p) acc[ot][q][p] = (f32x4){0.f, 0.f, 0.f, 0.f};

        #pragma unroll
        for (int q = 0; q < 2; ++q) {
            #pragma unroll
            for (int p = 0; p < 4; ++p) {
                const unsigned short* xp = &xt[cur][p][0][0] + 64 * q + 4 * c;
                #pragma unroll
                for (int s = 0; s < 5; ++s) {
                    union { short4v h[2]; short8 v8; } u;
                    u.h[0] = *(const short4v*)(xp + boff[s]);
                    u.h[1] = *(const short4v*)(xp + boff[s] + 4);
                    short8 bfr = u.v8;
                    acc[0][q][p] = __builtin_amdgcn_mfma_f32_16x16x32_bf16(afr[0][s], bfr, acc[0][q][p], 0, 0, 0);
                    acc[1][q][p] = __builtin_amdgcn_mfma_f32_16x16x32_bf16(afr[1][s], bfr, acc[1][q][p], 0, 0, 0);
                }
            }
        }

        // store: per (ot,q,r) one f32x4 at l = l0+128*lsub+64q+4c (contiguous)
        #pragma unroll
        for (int ot = 0; ot < 2; ++ot) {
            #pragma unroll
            for (int q = 0; q < 2; ++q) {
                #pragma unroll
                for (int r = 0; r < 4; ++r) {
                    int oc = 32 * a + 16 * ot + 4 * g + r;
                    float* yr = y + ((size_t)b * OC_N + oc) * L_LEN + l0 + 128 * lsub + 64 * q + 4 * c;
                    *(f32x4*)yr = (f32x4){ acc[ot][q][0][r], acc[ot][q][1][r],
                                           acc[ot][q][2][r], acc[ot][q][3][r] };
                }
            }
        }
        cur ^= 1;
    }
}

extern "C" void kernel_launch(void* const* d_in, const int* in_sizes, int n_in,
                              void* d_out, int out_size, void* d_ws, size_t ws_size,
                              hipStream_t stream) {
    const float* x  = (const float*)d_in[0];
    const int*   z  = (const int*)d_in[1];
    const float* s  = (const float*)d_in[2];
    const float* bw = (const float*)d_in[3];
    float* y = (float*)d_out;
    unsigned short* wpk = (unsigned short*)d_ws;   // 32*64*160*2 = 655 KB

    steer_weights<<<dim3(8, B_N), dim3(256), 0, stream>>>(z, s, bw, wpk);
    steer_conv_mfma<<<dim3(L_LEN / LGRP, B_N), dim3(256), 0, stream>>>(x, wpk, y);
}